// Round 6
// baseline (3661.996 us; speedup 1.0000x reference)
//
#include <hip/hip_runtime.h>
#include <hip/hip_bf16.h>
#include <math.h>

#define H_DIM 2880
#define F_DIM 2880
#define GU_DIM 5760
#define NE 16
#define NT 1024
#define TOPK 4
#define NIT 90            // K-steps (BK=32) for both GEMMs (H_DIM == F_DIM == 2880)

// ---- PROBE ROUND 2: round-5 pipelined GEMM bodies repeated in-kernel
// ---- (identical math; __syncthreads + acc re-zero per rep) to surface
// ---- their counter rows above the ~670us fill dispatches.
#define REP_G1 3
#define REP_G2 4

typedef float f32x4 __attribute__((ext_vector_type(4)));
typedef __bf16 bf16x8 __attribute__((ext_vector_type(8)));

__device__ __forceinline__ unsigned short f2bf(float f) {
    union { float f; unsigned u; } v; v.f = f;
    return (unsigned short)((v.u + 0x8000u) >> 16);   // round-half-up to bf16
}
__device__ __forceinline__ unsigned pk2(float a, float b) {
    return (unsigned)f2bf(a) | ((unsigned)f2bf(b) << 16);
}
// async global->LDS, 16B per lane; LDS dest is wave-uniform base + lane*16
__device__ __forceinline__ void gload16(const void* gsrc, void* ldst) {
    __builtin_amdgcn_global_load_lds(
        (const __attribute__((address_space(1))) unsigned int*)gsrc,
        (__attribute__((address_space(3))) unsigned int*)ldst,
        16, 0, 0);
}

// ---------------- x -> bf16 cast ----------------
__global__ __launch_bounds__(256) void castx_kernel(const float* __restrict__ x,
                                                    unsigned short* __restrict__ xb)
{
    int i = (blockIdx.x * 256 + threadIdx.x) * 8;
    float4 a = *(const float4*)(x + i);
    float4 b = *(const float4*)(x + i + 4);
    uint4 o;
    o.x = pk2(a.x, a.y); o.y = pk2(a.z, a.w);
    o.z = pk2(b.x, b.y); o.w = pk2(b.z, b.w);
    *(uint4*)(xb + i) = o;
}

// ---------------- router ----------------
__global__ __launch_bounds__(64) void router_kernel(
    const float* __restrict__ x, const float* __restrict__ rw, const float* __restrict__ rb,
    int* counts, int* topk_idx, float* topk_score)
{
    int t = blockIdx.x, lane = threadIdx.x;
    const float* xr = x + (size_t)t * H_DIM;
    float acc[NE];
#pragma unroll
    for (int e = 0; e < NE; e++) acc[e] = 0.f;
    for (int h = lane; h < H_DIM; h += 64) {
        float xv = xr[h];
#pragma unroll
        for (int e = 0; e < NE; e++) acc[e] += xv * rw[e * H_DIM + h];
    }
    float lg[NE];
#pragma unroll
    for (int e = 0; e < NE; e++) {
        float v = acc[e];
#pragma unroll
        for (int off = 32; off > 0; off >>= 1) v += __shfl_down(v, off, 64);
        lg[e] = v;
    }
    if (lane == 0) {
#pragma unroll
        for (int e = 0; e < NE; e++) lg[e] += rb[e];
        int mask = 0; float tv[TOPK]; int ti[TOPK];
        for (int k = 0; k < TOPK; k++) {
            float best = -1e30f; int bi = 0;
            for (int e = 0; e < NE; e++)
                if (!((mask >> e) & 1) && lg[e] > best) { best = lg[e]; bi = e; }
            mask |= 1 << bi; tv[k] = best; ti[k] = bi;
        }
        float m = tv[0], s = 0.f, ex[TOPK];
        for (int k = 0; k < TOPK; k++) { ex[k] = expf(tv[k] - m); s += ex[k]; }
        float inv = 1.f / s;
        for (int k = 0; k < TOPK; k++) {
            topk_idx[t * TOPK + k] = ti[k];
            topk_score[t * TOPK + k] = ex[k] * inv;
            atomicAdd(&counts[ti[k]], 1);
        }
    }
}

__global__ void offsets_kernel(const int* counts, int* offsets) {
    if (threadIdx.x == 0 && blockIdx.x == 0) {
        int s = 0;
        for (int e = 0; e < NE; e++) { offsets[e] = s; s += counts[e]; }
        offsets[NE] = s;
    }
}

__global__ void scatter_kernel(const int* topk_idx, const float* topk_score,
                               const int* offsets, int* fills, int* entry, float* entry_score,
                               int* slot_map)
{
    int t = blockIdx.x * blockDim.x + threadIdx.x;
    if (t >= NT) return;
    for (int k = 0; k < TOPK; k++) {
        int e = topk_idx[t * TOPK + k];
        int pos = atomicAdd(&fills[e], 1);
        int i = offsets[e] + pos;
        entry[i] = t | (k << 16);
        entry_score[i] = topk_score[t * TOPK + k];
        slot_map[t * TOPK + k] = i;
    }
}

// ===== shared pipelined-GEMM machinery (tile 256m x 128n, BK=32, 8 waves) =====
// depth-2 counted-vmcnt pipeline: per wave per K-step exactly 4 VMEM ops
// (2 global_load_lds for A + 2 dwordx4 for B). steady-state wait = vmcnt(4).

#define PIPE_ISSUE(ASRC0, ASRC1, BPTR, BSTRIDE, KK, NB, RS)                   \
    {                                                                         \
        gload16((ASRC0) + (KK), &As[NB][aoff0]);                              \
        gload16((ASRC1) + (KK), &As[NB][aoff1]);                              \
        RS[0] = *(const float4*)((BPTR) + (size_t)(KK) * (BSTRIDE));          \
        RS[1] = *(const float4*)((BPTR) + (size_t)((KK) + 1) * (BSTRIDE));    \
        asm volatile("" ::: "memory");                                        \
    }

#define PIPE_BWRITE(NB, RC)                                                   \
    {                                                                         \
        float4 t0_ = RC[0], t1_ = RC[1];                                      \
        *(unsigned*)&Bs[NB][bwr0] = pk2(t0_.x, t1_.x);                        \
        *(unsigned*)&Bs[NB][bwr1] = pk2(t0_.y, t1_.y);                        \
        *(unsigned*)&Bs[NB][bwr2] = pk2(t0_.z, t1_.z);                        \
        *(unsigned*)&Bs[NB][bwr3] = pk2(t0_.w, t1_.w);                        \
    }

#define PIPE_BARRIER()                                                        \
    asm volatile("s_waitcnt lgkmcnt(0)" ::: "memory");                        \
    __builtin_amdgcn_sched_barrier(0);                                        \
    __builtin_amdgcn_s_barrier();                                             \
    __builtin_amdgcn_sched_barrier(0);

#define PIPE_MFMA(CUR)                                                        \
    {                                                                         \
        bf16x8 af_[4], bq_[4];                                                \
        _Pragma("unroll") for (int i = 0; i < 4; i++)                         \
            af_[i] = *(const bf16x8*)&As[CUR][a_rd[i]];                       \
        _Pragma("unroll") for (int i = 0; i < 4; i++)                         \
            bq_[i] = *(const bf16x8*)&Bs[CUR][b_rd[i]];                       \
        _Pragma("unroll") for (int mi = 0; mi < 4; mi++)                      \
            _Pragma("unroll") for (int ni = 0; ni < 4; ni++)                  \
                acc[mi][ni] = __builtin_amdgcn_mfma_f32_16x16x32_bf16(        \
                    af_[mi], bq_[ni], acc[mi][ni], 0, 0, 0);                  \
    }

#define PIPE_BODY(ASRC0, ASRC1, BPTR, BSTRIDE, T, CUR, NB1, NB2, RISS, RCON)  \
    {                                                                         \
        bool more_ = (T) + 2 < NIT;                                           \
        if (more_) PIPE_ISSUE(ASRC0, ASRC1, BPTR, BSTRIDE, ((T) + 2) * 32, NB2, RISS); \
        PIPE_MFMA(CUR);                                                       \
        if ((T) + 1 < NIT) {                                                  \
            if (more_) { asm volatile("s_waitcnt vmcnt(4)" ::: "memory"); }   \
            else       { asm volatile("s_waitcnt vmcnt(0)" ::: "memory"); }   \
            PIPE_BWRITE(NB1, RCON);                                           \
            PIPE_BARRIER();                                                   \
        }                                                                     \
    }

// ---------------- GEMM1: act = GLU(x[tokens] @ gate_up_w[e] + b) ----------------
__global__ __launch_bounds__(512, 4) void gemm1_kernel(
    const unsigned short* __restrict__ xb, const float* __restrict__ gw, const float* __restrict__ gb,
    const int* __restrict__ counts, const int* __restrict__ offsets,
    const int* __restrict__ entry, unsigned short* __restrict__ act)
{
    int e = blockIdx.z;
    int cnt = counts[e];
    int m0 = blockIdx.y * 256;
    if (m0 >= cnt) return;
    int n0 = blockIdx.x * 128;
    int off = offsets[e];

    __shared__ __align__(16) unsigned short As[3][256 * 32];  // 16KB x3
    __shared__ __align__(16) unsigned short Bs[3][128 * 40];  // 10KB x3
    __shared__ int toks[256];

    int tid = threadIdx.x;
    if (tid < 256) {
        int r = m0 + tid;
        toks[tid] = entry[off + (r < cnt ? r : 0)] & 0xFFFF;
    }
    __syncthreads();

    int wv = tid >> 6, lane = tid & 63;

    // A gload: wave wv stages rows 32*wv..32*wv+31 (2 insts x 16 rows x 64B)
    int ar0 = 32 * wv + (lane >> 2);
    int ar1 = ar0 + 16;
    int ac = lane & 3;
    const unsigned short* asrc0 = xb + (size_t)toks[ar0] * H_DIM + 8 * (ac ^ ((ar0 >> 1) & 3));
    const unsigned short* asrc1 = xb + (size_t)toks[ar1] * H_DIM + 8 * (ac ^ ((ar1 >> 1) & 3));
    int aoff0 = (32 * wv) * 32;
    int aoff1 = (32 * wv + 16) * 32;

    // B staging: all 512 threads; thread owns 2 k-rows x 4 cols
    int n4 = tid & 31, ks = tid >> 5;          // ks in 0..15, k-base = ks*2
    const float* bptr = gw + (size_t)e * H_DIM * GU_DIM + (size_t)(ks * 2) * GU_DIM + n0 + n4 * 4;
    int bswz = (((ks >> 2) ^ (n4 & 3)) * 8) + (ks & 3) * 2;
    int bwr0 = (n4 * 4 + 0) * 40 + bswz;
    int bwr1 = (n4 * 4 + 1) * 40 + bswz;
    int bwr2 = (n4 * 4 + 2) * 40 + bswz;
    int bwr3 = (n4 * 4 + 3) * 40 + bswz;

    int wm = (wv >> 1) * 64, wn = (wv & 1) * 64;
    int r16 = lane & 15, q = lane >> 4;

    f32x4 acc[4][4] = {};
    int a_rd[4], b_rd[4];
#pragma unroll
    for (int i = 0; i < 4; i++) {
        int m = wm + i * 16 + r16;
        a_rd[i] = m * 32 + ((q ^ ((m >> 1) & 3)) * 8);
        int n = wn + i * 16 + r16;
        b_rd[i] = n * 40 + ((q ^ ((n >> 2) & 3)) * 8);
    }

    float4 rA[2], rB[2];
#pragma unroll 1
    for (int rep = 0; rep < REP_G1; rep++) {
        __syncthreads();   // quiesce LDS between reps (drains all counters)
#pragma unroll
        for (int mi = 0; mi < 4; mi++)
#pragma unroll
            for (int ni = 0; ni < 4; ni++) acc[mi][ni] = (f32x4){0.f, 0.f, 0.f, 0.f};

        // prologue: tiles 0 and 1 in flight; publish tile 0
        PIPE_ISSUE(asrc0, asrc1, bptr, GU_DIM, 0, 0, rA);
        PIPE_ISSUE(asrc0, asrc1, bptr, GU_DIM, 32, 1, rB);
        asm volatile("s_waitcnt vmcnt(4)" ::: "memory");
        PIPE_BWRITE(0, rA);
        PIPE_BARRIER();

        int c0 = 0;
        for (int it = 0; it < NIT; it += 2) {
            int c1 = c0 + 1; if (c1 == 3) c1 = 0;
            int c2 = c1 + 1; if (c2 == 3) c2 = 0;
            PIPE_BODY(asrc0, asrc1, bptr, GU_DIM, it,     c0, c1, c2, rA, rB);
            PIPE_BODY(asrc0, asrc1, bptr, GU_DIM, it + 1, c1, c2, c0, rB, rA);
            c0 = c2;
        }
    }

    // epilogue: bias + GLU (gate=even col, up=odd col), store bf16 act
    const float* gbp = gb + (size_t)e * GU_DIM;
#pragma unroll
    for (int ni = 0; ni < 4; ni++) {
        int col = n0 + wn + ni * 16 + r16;
        float bias = gbp[col];
#pragma unroll
        for (int mi = 0; mi < 4; mi++) {
#pragma unroll
            for (int r = 0; r < 4; r++) {
                float v = acc[mi][ni][r] + bias;
                float vo = __shfl_xor(v, 1, 64);
                float gate = (lane & 1) ? vo : v;
                float up   = (lane & 1) ? v  : vo;
                gate = fminf(gate, 7.0f);
                up = fminf(fmaxf(up, -7.0f), 7.0f);
                float glu = gate / (1.0f + expf(-1.702f * gate));
                float a = (up + 1.0f) * glu;
                int row = m0 + wm + mi * 16 + q * 4 + r;
                if (row < cnt && !(lane & 1))
                    act[(size_t)(off + row) * F_DIM + (col >> 1)] = f2bf(a);
            }
        }
    }
}

// ---------------- GEMM2: slot_out = score * (act @ down_w[e] + db) ----------------
__global__ __launch_bounds__(512, 4) void gemm2_kernel(
    const unsigned short* __restrict__ act, const float* __restrict__ dw, const float* __restrict__ db,
    const int* __restrict__ counts, const int* __restrict__ offsets,
    const float* __restrict__ entry_score, float* __restrict__ slot_out)
{
    int e = blockIdx.z;
    int cnt = counts[e];
    int m0 = blockIdx.y * 256;
    if (m0 >= cnt) return;
    int n0 = blockIdx.x * 128;
    int off = offsets[e];

    __shared__ __align__(16) unsigned short As[3][256 * 32];
    __shared__ __align__(16) unsigned short Bs[3][128 * 40];
    __shared__ float scs[256];

    int tid = threadIdx.x;
    if (tid < 256) {
        int r = m0 + tid;
        scs[tid] = entry_score[off + (r < cnt ? r : 0)];
    }
    __syncthreads();

    int wv = tid >> 6, lane = tid & 63;

    int ar0 = 32 * wv + (lane >> 2);
    int ar1 = ar0 + 16;
    int ac = lane & 3;
    const unsigned short* asrc0 = act + (size_t)(off + m0 + ar0) * F_DIM + 8 * (ac ^ ((ar0 >> 1) & 3));
    const unsigned short* asrc1 = act + (size_t)(off + m0 + ar1) * F_DIM + 8 * (ac ^ ((ar1 >> 1) & 3));
    int aoff0 = (32 * wv) * 32;
    int aoff1 = (32 * wv + 16) * 32;

    int n4 = tid & 31, ks = tid >> 5;
    int ncol = n0 + n4 * 4;
    // ragged last n-tile (2880 % 128 = 64): clamp the address (junk cols are
    // computed but never stored) so every wave issues a uniform 2-op B batch.
    int ncc = (ncol < H_DIM) ? ncol : (H_DIM - 4);
    const float* bptr = dw + (size_t)e * F_DIM * H_DIM + (size_t)(ks * 2) * H_DIM + ncc;
    int bswz = (((ks >> 2) ^ (n4 & 3)) * 8) + (ks & 3) * 2;
    int bwr0 = (n4 * 4 + 0) * 40 + bswz;
    int bwr1 = (n4 * 4 + 1) * 40 + bswz;
    int bwr2 = (n4 * 4 + 2) * 40 + bswz;
    int bwr3 = (n4 * 4 + 3) * 40 + bswz;

    int wm = (wv >> 1) * 64, wn = (wv & 1) * 64;
    int r16 = lane & 15, q = lane >> 4;

    f32x4 acc[4][4] = {};
    int a_rd[4], b_rd[4];
#pragma unroll
    for (int i = 0; i < 4; i++) {
        int m = wm + i * 16 + r16;
        a_rd[i] = m * 32 + ((q ^ ((m >> 1) & 3)) * 8);
        int n = wn + i * 16 + r16;
        b_rd[i] = n * 40 + ((q ^ ((n >> 2) & 3)) * 8);
    }

    float4 rA[2], rB[2];
#pragma unroll 1
    for (int rep = 0; rep < REP_G2; rep++) {
        __syncthreads();
#pragma unroll
        for (int mi = 0; mi < 4; mi++)
#pragma unroll
            for (int ni = 0; ni < 4; ni++) acc[mi][ni] = (f32x4){0.f, 0.f, 0.f, 0.f};

        PIPE_ISSUE(asrc0, asrc1, bptr, H_DIM, 0, 0, rA);
        PIPE_ISSUE(asrc0, asrc1, bptr, H_DIM, 32, 1, rB);
        asm volatile("s_waitcnt vmcnt(4)" ::: "memory");
        PIPE_BWRITE(0, rA);
        PIPE_BARRIER();

        int c0 = 0;
        for (int it = 0; it < NIT; it += 2) {
            int c1 = c0 + 1; if (c1 == 3) c1 = 0;
            int c2 = c1 + 1; if (c2 == 3) c2 = 0;
            PIPE_BODY(asrc0, asrc1, bptr, H_DIM, it,     c0, c1, c2, rA, rB);
            PIPE_BODY(asrc0, asrc1, bptr, H_DIM, it + 1, c1, c2, c0, rB, rA);
            c0 = c2;
        }
    }

    const float* dbp = db + (size_t)e * H_DIM;
#pragma unroll
    for (int ni = 0; ni < 4; ni++) {
        int col = n0 + wn + ni * 16 + r16;
        float bias = (col < H_DIM) ? dbp[col] : 0.f;
#pragma unroll
        for (int mi = 0; mi < 4; mi++) {
#pragma unroll
            for (int r = 0; r < 4; r++) {
                int lr = wm + mi * 16 + q * 4 + r;
                if (m0 + lr < cnt && col < H_DIM) {
                    float v = (acc[mi][ni][r] + bias) * scs[lr];
                    slot_out[(size_t)(off + m0 + lr) * H_DIM + col] = v;
                }
            }
        }
    }
}

// ---------------- gather: out[t] = sum of the token's 4 slot rows ----------------
__global__ __launch_bounds__(256) void gather_kernel(
    const float* __restrict__ slot_out, const int* __restrict__ slot_map,
    float* __restrict__ out)
{
    int t = blockIdx.x;
    int s0 = slot_map[t * TOPK + 0];
    int s1 = slot_map[t * TOPK + 1];
    int s2 = slot_map[t * TOPK + 2];
    int s3 = slot_map[t * TOPK + 3];
    const float* r0 = slot_out + (size_t)s0 * H_DIM;
    const float* r1 = slot_out + (size_t)s1 * H_DIM;
    const float* r2 = slot_out + (size_t)s2 * H_DIM;
    const float* r3 = slot_out + (size_t)s3 * H_DIM;
    float* op = out + (size_t)t * H_DIM;
    for (int h = threadIdx.x * 4; h < H_DIM; h += 1024) {
        f32x4 v = *(const f32x4*)(r0 + h) + *(const f32x4*)(r1 + h)
                + *(const f32x4*)(r2 + h) + *(const f32x4*)(r3 + h);
        *(f32x4*)(op + h) = v;
    }
}

// ---------------- launch ----------------
extern "C" void kernel_launch(void* const* d_in, const int* in_sizes, int n_in,
                              void* d_out, int out_size, void* d_ws, size_t ws_size,
                              hipStream_t stream)
{
    const float* x  = (const float*)d_in[0];
    const float* rw = (const float*)d_in[1];
    const float* rb = (const float*)d_in[2];
    const float* gw = (const float*)d_in[3];
    const float* gb = (const float*)d_in[4];
    const float* dw = (const float*)d_in[5];
    const float* db = (const float*)d_in[6];
    float* out = (float*)d_out;

    char* ws = (char*)d_ws;
    int*   counts      = (int*)(ws);
    int*   fills       = (int*)(ws + 64);
    int*   offsets     = (int*)(ws + 128);
    int*   topk_idx    = (int*)(ws + 256);
    float* topk_score  = (float*)(ws + 16640);
    int*   entry       = (int*)(ws + 33024);
    float* entry_score = (float*)(ws + 49408);
    int*   slot_map    = (int*)(ws + 65792);
    unsigned short* act = (unsigned short*)(ws + 131072);   // 4352 x 2880 bf16 (256-row slack for gload overread)
    unsigned short* xb  = (unsigned short*)(ws + 25198592); // 1024 x 2880 bf16
    float* slot_out     = (float*)(ws + 31096832);          // 4096 x 2880 f32

    hipMemsetAsync(ws, 0, 256, stream);   // counts + fills

    castx_kernel<<<1440, 256, 0, stream>>>(x, xb);
    router_kernel<<<NT, 64, 0, stream>>>(x, rw, rb, counts, topk_idx, topk_score);
    offsets_kernel<<<1, 32, 0, stream>>>(counts, offsets);
    scatter_kernel<<<4, 256, 0, stream>>>(topk_idx, topk_score, offsets, fills, entry, entry_score, slot_map);
    gemm1_kernel<<<dim3(45, 4, NE), 512, 0, stream>>>(xb, gw, gb, counts, offsets, entry, act);
    gemm2_kernel<<<dim3(23, 4, NE), 512, 0, stream>>>(act, dw, db, counts, offsets, entry_score, slot_out);
    gather_kernel<<<NT, 256, 0, stream>>>(slot_out, slot_map, out);
}

// Round 7
// 2184.530 us; speedup vs baseline: 1.6763x; 1.6763x over previous
//
#include <hip/hip_runtime.h>
#include <hip/hip_bf16.h>
#include <math.h>

#define H_DIM 2880
#define F_DIM 2880
#define GU_DIM 5760
#define NE 16
#define NT 1024
#define TOPK 4
#define NIT 90            // K-steps (BK=32) for both GEMMs (H_DIM == F_DIM == 2880)

typedef float f32x4 __attribute__((ext_vector_type(4)));
typedef __bf16 bf16x8 __attribute__((ext_vector_type(8)));

__device__ __forceinline__ unsigned short f2bf(float f) {
    union { float f; unsigned u; } v; v.f = f;
    return (unsigned short)((v.u + 0x8000u) >> 16);   // round-half-up to bf16
}
__device__ __forceinline__ unsigned pk2(float a, float b) {
    return (unsigned)f2bf(a) | ((unsigned)f2bf(b) << 16);
}
// async global->LDS, 16B per lane; LDS dest is wave-uniform base + lane*16
__device__ __forceinline__ void gload16(const void* gsrc, void* ldst) {
    __builtin_amdgcn_global_load_lds(
        (const __attribute__((address_space(1))) unsigned int*)gsrc,
        (__attribute__((address_space(3))) unsigned int*)ldst,
        16, 0, 0);
}

// ---------------- x -> bf16 cast ----------------
__global__ __launch_bounds__(256) void castx_kernel(const float* __restrict__ x,
                                                    unsigned short* __restrict__ xb)
{
    int i = (blockIdx.x * 256 + threadIdx.x) * 8;
    float4 a = *(const float4*)(x + i);
    float4 b = *(const float4*)(x + i + 4);
    uint4 o;
    o.x = pk2(a.x, a.y); o.y = pk2(a.z, a.w);
    o.z = pk2(b.x, b.y); o.w = pk2(b.z, b.w);
    *(uint4*)(xb + i) = o;
}

// ---------------- router ----------------
__global__ __launch_bounds__(64) void router_kernel(
    const float* __restrict__ x, const float* __restrict__ rw, const float* __restrict__ rb,
    int* counts, int* topk_idx, float* topk_score)
{
    int t = blockIdx.x, lane = threadIdx.x;
    const float* xr = x + (size_t)t * H_DIM;
    float acc[NE];
#pragma unroll
    for (int e = 0; e < NE; e++) acc[e] = 0.f;
    for (int h = lane; h < H_DIM; h += 64) {
        float xv = xr[h];
#pragma unroll
        for (int e = 0; e < NE; e++) acc[e] += xv * rw[e * H_DIM + h];
    }
    float lg[NE];
#pragma unroll
    for (int e = 0; e < NE; e++) {
        float v = acc[e];
#pragma unroll
        for (int off = 32; off > 0; off >>= 1) v += __shfl_down(v, off, 64);
        lg[e] = v;
    }
    if (lane == 0) {
#pragma unroll
        for (int e = 0; e < NE; e++) lg[e] += rb[e];
        int mask = 0; float tv[TOPK]; int ti[TOPK];
        for (int k = 0; k < TOPK; k++) {
            float best = -1e30f; int bi = 0;
            for (int e = 0; e < NE; e++)
                if (!((mask >> e) & 1) && lg[e] > best) { best = lg[e]; bi = e; }
            mask |= 1 << bi; tv[k] = best; ti[k] = bi;
        }
        float m = tv[0], s = 0.f, ex[TOPK];
        for (int k = 0; k < TOPK; k++) { ex[k] = expf(tv[k] - m); s += ex[k]; }
        float inv = 1.f / s;
        for (int k = 0; k < TOPK; k++) {
            topk_idx[t * TOPK + k] = ti[k];
            topk_score[t * TOPK + k] = ex[k] * inv;
            atomicAdd(&counts[ti[k]], 1);
        }
    }
}

__global__ void offsets_kernel(const int* counts, int* offsets) {
    if (threadIdx.x == 0 && blockIdx.x == 0) {
        int s = 0;
        for (int e = 0; e < NE; e++) { offsets[e] = s; s += counts[e]; }
        offsets[NE] = s;
    }
}

__global__ void scatter_kernel(const int* topk_idx, const float* topk_score,
                               const int* offsets, int* fills, int* entry, float* entry_score,
                               int* slot_map)
{
    int t = blockIdx.x * blockDim.x + threadIdx.x;
    if (t >= NT) return;
    for (int k = 0; k < TOPK; k++) {
        int e = topk_idx[t * TOPK + k];
        int pos = atomicAdd(&fills[e], 1);
        int i = offsets[e] + pos;
        entry[i] = t | (k << 16);
        entry_score[i] = topk_score[t * TOPK + k];
        slot_map[t * TOPK + k] = i;
    }
}

// ===== pipelined GEMM machinery (tile 256m x 128n, BK=32, 8 waves) =====
// depth-2 counted-vmcnt pipeline (round-5, g1'=429us measured) + NEW
// conflict-free B staging:
//   thread t: kp = l0l1|l4|w0 (k-pair 0..15), qd = l2l3|l5|w1w2 (col-quad 0..31)
//   loads: rows {2kp, 2kp+1} x 4 cols (per wave-op: 8 x 128B segments, L2-aligned)
//   Bs layout: row n stride 40 shorts; chunk g at slot g ^ s(n), s(n)=((n>>2)^(n>>4))&3
//   write op j: b32 at n=4qd+j -> bank = l0+2l1+4(l4^l2^l5)+8(l3^w0^w1)+16l2 + Cj
//   => exactly 2 lanes/bank (free, m136). Read b_rd uses same s(n): uniform 8/group.

#define PIPE_ISSUE(ASRC0, ASRC1, BPTR, BSTRIDE, KK, NB, RS)                   \
    {                                                                         \
        gload16((ASRC0) + (KK), &As[NB][aoff0]);                              \
        gload16((ASRC1) + (KK), &As[NB][aoff1]);                              \
        RS[0] = *(const float4*)((BPTR) + (size_t)(KK) * (BSTRIDE));          \
        RS[1] = *(const float4*)((BPTR) + (size_t)((KK) + 1) * (BSTRIDE));    \
        asm volatile("" ::: "memory");                                        \
    }

#define PIPE_BWRITE(NB, RC)                                                   \
    {                                                                         \
        float4 t0_ = RC[0], t1_ = RC[1];                                      \
        *(unsigned*)&Bs[NB][bwr0] = pk2(t0_.x, t1_.x);                        \
        *(unsigned*)&Bs[NB][bwr1] = pk2(t0_.y, t1_.y);                        \
        *(unsigned*)&Bs[NB][bwr2] = pk2(t0_.z, t1_.z);                        \
        *(unsigned*)&Bs[NB][bwr3] = pk2(t0_.w, t1_.w);                        \
    }

#define PIPE_BARRIER()                                                        \
    asm volatile("s_waitcnt lgkmcnt(0)" ::: "memory");                        \
    __builtin_amdgcn_sched_barrier(0);                                        \
    __builtin_amdgcn_s_barrier();                                             \
    __builtin_amdgcn_sched_barrier(0);

#define PIPE_MFMA(CUR)                                                        \
    {                                                                         \
        bf16x8 af_[4], bq_[4];                                                \
        _Pragma("unroll") for (int i = 0; i < 4; i++)                         \
            af_[i] = *(const bf16x8*)&As[CUR][a_rd[i]];                       \
        _Pragma("unroll") for (int i = 0; i < 4; i++)                         \
            bq_[i] = *(const bf16x8*)&Bs[CUR][b_rd[i]];                       \
        _Pragma("unroll") for (int mi = 0; mi < 4; mi++)                      \
            _Pragma("unroll") for (int ni = 0; ni < 4; ni++)                  \
                acc[mi][ni] = __builtin_amdgcn_mfma_f32_16x16x32_bf16(        \
                    af_[mi], bq_[ni], acc[mi][ni], 0, 0, 0);                  \
    }

#define PIPE_BODY(ASRC0, ASRC1, BPTR, BSTRIDE, T, CUR, NB1, NB2, RISS, RCON)  \
    {                                                                         \
        bool more_ = (T) + 2 < NIT;                                           \
        if (more_) PIPE_ISSUE(ASRC0, ASRC1, BPTR, BSTRIDE, ((T) + 2) * 32, NB2, RISS); \
        PIPE_MFMA(CUR);                                                       \
        if ((T) + 1 < NIT) {                                                  \
            if (more_) { asm volatile("s_waitcnt vmcnt(4)" ::: "memory"); }   \
            else       { asm volatile("s_waitcnt vmcnt(0)" ::: "memory"); }   \
            PIPE_BWRITE(NB1, RCON);                                           \
            PIPE_BARRIER();                                                   \
        }                                                                     \
    }

// B write-address helper: col n = 4*qd + j, chunk slot (kp>>2) ^ s(n),
// intra-chunk unsigned index kp&3  (addresses in shorts)
__device__ __forceinline__ int mk_bwr(int qd, int j, int kp) {
    int n = 4 * qd + j;
    int sn = ((n >> 2) ^ (n >> 4)) & 3;
    return n * 40 + (((kp >> 2) ^ sn) * 8) + (kp & 3) * 2;
}

// ---------------- GEMM1: act = GLU(x[tokens] @ gate_up_w[e] + b) ----------------
__global__ __launch_bounds__(512, 4) void gemm1_kernel(
    const unsigned short* __restrict__ xb, const float* __restrict__ gw, const float* __restrict__ gb,
    const int* __restrict__ counts, const int* __restrict__ offsets,
    const int* __restrict__ entry, unsigned short* __restrict__ act)
{
    int e = blockIdx.z;
    int cnt = counts[e];
    int m0 = blockIdx.y * 256;
    if (m0 >= cnt) return;
    int n0 = blockIdx.x * 128;
    int off = offsets[e];

    __shared__ __align__(16) unsigned short As[3][256 * 32];  // 16KB x3
    __shared__ __align__(16) unsigned short Bs[3][128 * 40];  // 10KB x3
    __shared__ int toks[256];

    int tid = threadIdx.x;
    if (tid < 256) {
        int r = m0 + tid;
        toks[tid] = entry[off + (r < cnt ? r : 0)] & 0xFFFF;
    }
    __syncthreads();

    int wv = tid >> 6, lane = tid & 63;

    // A gload: wave wv stages rows 32*wv..32*wv+31 (2 insts x 16 rows x 64B)
    int ar0 = 32 * wv + (lane >> 2);
    int ar1 = ar0 + 16;
    int ac = lane & 3;
    const unsigned short* asrc0 = xb + (size_t)toks[ar0] * H_DIM + 8 * (ac ^ ((ar0 >> 1) & 3));
    const unsigned short* asrc1 = xb + (size_t)toks[ar1] * H_DIM + 8 * (ac ^ ((ar1 >> 1) & 3));
    int aoff0 = (32 * wv) * 32;
    int aoff1 = (32 * wv + 16) * 32;

    // B staging: conflict-free assignment (see header comment)
    int kp = (lane & 3) | (((lane >> 4) & 1) << 2) | ((wv & 1) << 3);      // k-pair 0..15
    int qd = ((lane >> 2) & 3) | (((lane >> 5) & 1) << 2) | ((wv >> 1) << 3); // col-quad 0..31
    const float* bptr = gw + (size_t)e * H_DIM * GU_DIM + (size_t)(2 * kp) * GU_DIM + n0 + 4 * qd;
    int bwr0 = mk_bwr(qd, 0, kp);
    int bwr1 = mk_bwr(qd, 1, kp);
    int bwr2 = mk_bwr(qd, 2, kp);
    int bwr3 = mk_bwr(qd, 3, kp);

    int wm = (wv >> 1) * 64, wn = (wv & 1) * 64;
    int r16 = lane & 15, q = lane >> 4;

    f32x4 acc[4][4] = {};
    int a_rd[4], b_rd[4];
#pragma unroll
    for (int i = 0; i < 4; i++) {
        int m = wm + i * 16 + r16;
        a_rd[i] = m * 32 + ((q ^ ((m >> 1) & 3)) * 8);
        int n = wn + i * 16 + r16;
        int sn = ((n >> 2) ^ (n >> 4)) & 3;
        b_rd[i] = n * 40 + ((q ^ sn) * 8);
    }

    float4 rA[2], rB[2];
    // prologue: tiles 0 and 1 in flight; publish tile 0
    PIPE_ISSUE(asrc0, asrc1, bptr, GU_DIM, 0, 0, rA);
    PIPE_ISSUE(asrc0, asrc1, bptr, GU_DIM, 32, 1, rB);
    asm volatile("s_waitcnt vmcnt(4)" ::: "memory");
    PIPE_BWRITE(0, rA);
    PIPE_BARRIER();

    int c0 = 0;
    for (int it = 0; it < NIT; it += 2) {
        int c1 = c0 + 1; if (c1 == 3) c1 = 0;
        int c2 = c1 + 1; if (c2 == 3) c2 = 0;
        PIPE_BODY(asrc0, asrc1, bptr, GU_DIM, it,     c0, c1, c2, rA, rB);
        PIPE_BODY(asrc0, asrc1, bptr, GU_DIM, it + 1, c1, c2, c0, rB, rA);
        c0 = c2;
    }

    // epilogue: bias + GLU (gate=even col, up=odd col), store bf16 act
    const float* gbp = gb + (size_t)e * GU_DIM;
#pragma unroll
    for (int ni = 0; ni < 4; ni++) {
        int col = n0 + wn + ni * 16 + r16;
        float bias = gbp[col];
#pragma unroll
        for (int mi = 0; mi < 4; mi++) {
#pragma unroll
            for (int r = 0; r < 4; r++) {
                float v = acc[mi][ni][r] + bias;
                float vo = __shfl_xor(v, 1, 64);
                float gate = (lane & 1) ? vo : v;
                float up   = (lane & 1) ? v  : vo;
                gate = fminf(gate, 7.0f);
                up = fminf(fmaxf(up, -7.0f), 7.0f);
                float glu = gate / (1.0f + expf(-1.702f * gate));
                float a = (up + 1.0f) * glu;
                int row = m0 + wm + mi * 16 + q * 4 + r;
                if (row < cnt && !(lane & 1))
                    act[(size_t)(off + row) * F_DIM + (col >> 1)] = f2bf(a);
            }
        }
    }
}

// ---------------- GEMM2: slot_out = score * (act @ down_w[e] + db) ----------------
__global__ __launch_bounds__(512, 4) void gemm2_kernel(
    const unsigned short* __restrict__ act, const float* __restrict__ dw, const float* __restrict__ db,
    const int* __restrict__ counts, const int* __restrict__ offsets,
    const float* __restrict__ entry_score, float* __restrict__ slot_out)
{
    int e = blockIdx.z;
    int cnt = counts[e];
    int m0 = blockIdx.y * 256;
    if (m0 >= cnt) return;
    int n0 = blockIdx.x * 128;
    int off = offsets[e];

    __shared__ __align__(16) unsigned short As[3][256 * 32];
    __shared__ __align__(16) unsigned short Bs[3][128 * 40];
    __shared__ float scs[256];

    int tid = threadIdx.x;
    if (tid < 256) {
        int r = m0 + tid;
        scs[tid] = entry_score[off + (r < cnt ? r : 0)];
    }
    __syncthreads();

    int wv = tid >> 6, lane = tid & 63;

    int ar0 = 32 * wv + (lane >> 2);
    int ar1 = ar0 + 16;
    int ac = lane & 3;
    const unsigned short* asrc0 = act + (size_t)(off + m0 + ar0) * F_DIM + 8 * (ac ^ ((ar0 >> 1) & 3));
    const unsigned short* asrc1 = act + (size_t)(off + m0 + ar1) * F_DIM + 8 * (ac ^ ((ar1 >> 1) & 3));
    int aoff0 = (32 * wv) * 32;
    int aoff1 = (32 * wv + 16) * 32;

    int kp = (lane & 3) | (((lane >> 4) & 1) << 2) | ((wv & 1) << 3);
    int qd = ((lane >> 2) & 3) | (((lane >> 5) & 1) << 2) | ((wv >> 1) << 3);
    int ncol = n0 + 4 * qd;
    // ragged last n-tile (2880 % 128 = 64): clamp the address (junk cols are
    // computed but never stored) so every wave issues a uniform 2-op B batch.
    int ncc = (ncol < H_DIM) ? ncol : (H_DIM - 4);
    const float* bptr = dw + (size_t)e * F_DIM * H_DIM + (size_t)(2 * kp) * H_DIM + ncc;
    int bwr0 = mk_bwr(qd, 0, kp);
    int bwr1 = mk_bwr(qd, 1, kp);
    int bwr2 = mk_bwr(qd, 2, kp);
    int bwr3 = mk_bwr(qd, 3, kp);

    int wm = (wv >> 1) * 64, wn = (wv & 1) * 64;
    int r16 = lane & 15, q = lane >> 4;

    f32x4 acc[4][4] = {};
    int a_rd[4], b_rd[4];
#pragma unroll
    for (int i = 0; i < 4; i++) {
        int m = wm + i * 16 + r16;
        a_rd[i] = m * 32 + ((q ^ ((m >> 1) & 3)) * 8);
        int n = wn + i * 16 + r16;
        int sn = ((n >> 2) ^ (n >> 4)) & 3;
        b_rd[i] = n * 40 + ((q ^ sn) * 8);
    }

    float4 rA[2], rB[2];
    PIPE_ISSUE(asrc0, asrc1, bptr, H_DIM, 0, 0, rA);
    PIPE_ISSUE(asrc0, asrc1, bptr, H_DIM, 32, 1, rB);
    asm volatile("s_waitcnt vmcnt(4)" ::: "memory");
    PIPE_BWRITE(0, rA);
    PIPE_BARRIER();

    int c0 = 0;
    for (int it = 0; it < NIT; it += 2) {
        int c1 = c0 + 1; if (c1 == 3) c1 = 0;
        int c2 = c1 + 1; if (c2 == 3) c2 = 0;
        PIPE_BODY(asrc0, asrc1, bptr, H_DIM, it,     c0, c1, c2, rA, rB);
        PIPE_BODY(asrc0, asrc1, bptr, H_DIM, it + 1, c1, c2, c0, rB, rA);
        c0 = c2;
    }

    const float* dbp = db + (size_t)e * H_DIM;
#pragma unroll
    for (int ni = 0; ni < 4; ni++) {
        int col = n0 + wn + ni * 16 + r16;
        float bias = (col < H_DIM) ? dbp[col] : 0.f;
#pragma unroll
        for (int mi = 0; mi < 4; mi++) {
#pragma unroll
            for (int r = 0; r < 4; r++) {
                int lr = wm + mi * 16 + q * 4 + r;
                if (m0 + lr < cnt && col < H_DIM) {
                    float v = (acc[mi][ni][r] + bias) * scs[lr];
                    slot_out[(size_t)(off + m0 + lr) * H_DIM + col] = v;
                }
            }
        }
    }
}

// ---------------- gather: out[t] = sum of the token's 4 slot rows ----------------
__global__ __launch_bounds__(256) void gather_kernel(
    const float* __restrict__ slot_out, const int* __restrict__ slot_map,
    float* __restrict__ out)
{
    int t = blockIdx.x;
    int s0 = slot_map[t * TOPK + 0];
    int s1 = slot_map[t * TOPK + 1];
    int s2 = slot_map[t * TOPK + 2];
    int s3 = slot_map[t * TOPK + 3];
    const float* r0 = slot_out + (size_t)s0 * H_DIM;
    const float* r1 = slot_out + (size_t)s1 * H_DIM;
    const float* r2 = slot_out + (size_t)s2 * H_DIM;
    const float* r3 = slot_out + (size_t)s3 * H_DIM;
    float* op = out + (size_t)t * H_DIM;
    for (int h = threadIdx.x * 4; h < H_DIM; h += 1024) {
        f32x4 v = *(const f32x4*)(r0 + h) + *(const f32x4*)(r1 + h)
                + *(const f32x4*)(r2 + h) + *(const f32x4*)(r3 + h);
        *(f32x4*)(op + h) = v;
    }
}

// ---------------- launch ----------------
extern "C" void kernel_launch(void* const* d_in, const int* in_sizes, int n_in,
                              void* d_out, int out_size, void* d_ws, size_t ws_size,
                              hipStream_t stream)
{
    const float* x  = (const float*)d_in[0];
    const float* rw = (const float*)d_in[1];
    const float* rb = (const float*)d_in[2];
    const float* gw = (const float*)d_in[3];
    const float* gb = (const float*)d_in[4];
    const float* dw = (const float*)d_in[5];
    const float* db = (const float*)d_in[6];
    float* out = (float*)d_out;

    char* ws = (char*)d_ws;
    int*   counts      = (int*)(ws);
    int*   fills       = (int*)(ws + 64);
    int*   offsets     = (int*)(ws + 128);
    int*   topk_idx    = (int*)(ws + 256);
    float* topk_score  = (float*)(ws + 16640);
    int*   entry       = (int*)(ws + 33024);
    float* entry_score = (float*)(ws + 49408);
    int*   slot_map    = (int*)(ws + 65792);
    unsigned short* act = (unsigned short*)(ws + 131072);   // 4352 x 2880 bf16 (256-row slack for gload overread)
    unsigned short* xb  = (unsigned short*)(ws + 25198592); // 1024 x 2880 bf16
    float* slot_out     = (float*)(ws + 31096832);          // 4096 x 2880 f32

    hipMemsetAsync(ws, 0, 256, stream);   // counts + fills

    castx_kernel<<<1440, 256, 0, stream>>>(x, xb);
    router_kernel<<<NT, 64, 0, stream>>>(x, rw, rb, counts, topk_idx, topk_score);
    offsets_kernel<<<1, 32, 0, stream>>>(counts, offsets);
    scatter_kernel<<<4, 256, 0, stream>>>(topk_idx, topk_score, offsets, fills, entry, entry_score, slot_map);
    gemm1_kernel<<<dim3(45, 4, NE), 512, 0, stream>>>(xb, gw, gb, counts, offsets, entry, act);
    gemm2_kernel<<<dim3(23, 4, NE), 512, 0, stream>>>(act, dw, db, counts, offsets, entry_score, slot_out);
    gather_kernel<<<NT, 256, 0, stream>>>(slot_out, slot_map, out);
}

// Round 8
// 2118.376 us; speedup vs baseline: 1.7287x; 1.0312x over previous
//
#include <hip/hip_runtime.h>
#include <hip/hip_bf16.h>
#include <math.h>

#define H_DIM 2880
#define F_DIM 2880
#define GU_DIM 5760
#define NE 16
#define NT 1024
#define TOPK 4
#define NIT 90            // K-steps (BK=32) for both GEMMs (H_DIM == F_DIM == 2880)

typedef float f32x4 __attribute__((ext_vector_type(4)));
typedef __bf16 bf16x8 __attribute__((ext_vector_type(8)));

__device__ __forceinline__ unsigned short f2bf(float f) {
    union { float f; unsigned u; } v; v.f = f;
    return (unsigned short)((v.u + 0x8000u) >> 16);   // round-half-up to bf16
}
__device__ __forceinline__ unsigned pk2(float a, float b) {
    return (unsigned)f2bf(a) | ((unsigned)f2bf(b) << 16);
}
// async global->LDS, 16B per lane; LDS dest is wave-uniform base + lane*16
__device__ __forceinline__ void gload16(const void* gsrc, void* ldst) {
    __builtin_amdgcn_global_load_lds(
        (const __attribute__((address_space(1))) unsigned int*)gsrc,
        (__attribute__((address_space(3))) unsigned int*)ldst,
        16, 0, 0);
}

// ---------------- x -> bf16 cast ----------------
__global__ __launch_bounds__(256) void castx_kernel(const float* __restrict__ x,
                                                    unsigned short* __restrict__ xb)
{
    int i = (blockIdx.x * 256 + threadIdx.x) * 8;
    float4 a = *(const float4*)(x + i);
    float4 b = *(const float4*)(x + i + 4);
    uint4 o;
    o.x = pk2(a.x, a.y); o.y = pk2(a.z, a.w);
    o.z = pk2(b.x, b.y); o.w = pk2(b.z, b.w);
    *(uint4*)(xb + i) = o;
}

// ---------------- router ----------------
__global__ __launch_bounds__(64) void router_kernel(
    const float* __restrict__ x, const float* __restrict__ rw, const float* __restrict__ rb,
    int* counts, int* topk_idx, float* topk_score)
{
    int t = blockIdx.x, lane = threadIdx.x;
    const float* xr = x + (size_t)t * H_DIM;
    float acc[NE];
#pragma unroll
    for (int e = 0; e < NE; e++) acc[e] = 0.f;
    for (int h = lane; h < H_DIM; h += 64) {
        float xv = xr[h];
#pragma unroll
        for (int e = 0; e < NE; e++) acc[e] += xv * rw[e * H_DIM + h];
    }
    float lg[NE];
#pragma unroll
    for (int e = 0; e < NE; e++) {
        float v = acc[e];
#pragma unroll
        for (int off = 32; off > 0; off >>= 1) v += __shfl_down(v, off, 64);
        lg[e] = v;
    }
    if (lane == 0) {
#pragma unroll
        for (int e = 0; e < NE; e++) lg[e] += rb[e];
        int mask = 0; float tv[TOPK]; int ti[TOPK];
        for (int k = 0; k < TOPK; k++) {
            float best = -1e30f; int bi = 0;
            for (int e = 0; e < NE; e++)
                if (!((mask >> e) & 1) && lg[e] > best) { best = lg[e]; bi = e; }
            mask |= 1 << bi; tv[k] = best; ti[k] = bi;
        }
        float m = tv[0], s = 0.f, ex[TOPK];
        for (int k = 0; k < TOPK; k++) { ex[k] = expf(tv[k] - m); s += ex[k]; }
        float inv = 1.f / s;
        for (int k = 0; k < TOPK; k++) {
            topk_idx[t * TOPK + k] = ti[k];
            topk_score[t * TOPK + k] = ex[k] * inv;
            atomicAdd(&counts[ti[k]], 1);
        }
    }
}

__global__ void offsets_kernel(const int* counts, int* offsets) {
    if (threadIdx.x == 0 && blockIdx.x == 0) {
        int s = 0;
        for (int e = 0; e < NE; e++) { offsets[e] = s; s += counts[e]; }
        offsets[NE] = s;
    }
}

__global__ void scatter_kernel(const int* topk_idx, const float* topk_score,
                               const int* offsets, int* fills, int* entry, float* entry_score,
                               int* slot_map)
{
    int t = blockIdx.x * blockDim.x + threadIdx.x;
    if (t >= NT) return;
    for (int k = 0; k < TOPK; k++) {
        int e = topk_idx[t * TOPK + k];
        int pos = atomicAdd(&fills[e], 1);
        int i = offsets[e] + pos;
        entry[i] = t | (k << 16);
        entry_score[i] = topk_score[t * TOPK + k];
        slot_map[t * TOPK + k] = i;
    }
}

// ===== pipelined GEMM machinery (tile 256m x 256n, BK=32, 16 waves / 1024 thr) =====
// depth-2 counted-vmcnt pipeline. Per wave per K-step exactly 3 VMEM ops:
//   1 global_load_lds (A: 16 rows x 64B) + 2 float4 loads (B: wave's k-row-pair
//   {2wv, 2wv+1}, each wave-instr = ONE FULL 1KB CONTIGUOUS ROW -> max DRAM/L2
//   efficiency, the R4-measured best pattern). steady-state wait = vmcnt(3).
// Bs layout: row n (0..255) stride 40 shorts; chunk q (k=8q..8q+7) at slot
//   q ^ sn, sn = ((n>>3)^(n>>5))&3  -> sn constant within each 8-row b128 phase
//   group => B-frag ds_read_b128 conflict-free. Writes 4-way (irreducible here),
//   ~400 cyc/step on a pipe with headroom.

#define PIPE_ISSUE(ASRC, BPTR, BSTRIDE, KK, NB, RS)                           \
    {                                                                         \
        gload16((ASRC) + (KK), &As[NB][aoff]);                                \
        RS[0] = *(const float4*)((BPTR) + (size_t)(KK) * (BSTRIDE));          \
        RS[1] = *(const float4*)((BPTR) + (size_t)((KK) + 1) * (BSTRIDE));    \
        asm volatile("" ::: "memory");                                        \
    }

#define PIPE_BWRITE(NB, RC)                                                   \
    {                                                                         \
        float4 t0_ = RC[0], t1_ = RC[1];                                      \
        *(unsigned*)&Bs[NB][bwr0] = pk2(t0_.x, t1_.x);                        \
        *(unsigned*)&Bs[NB][bwr1] = pk2(t0_.y, t1_.y);                        \
        *(unsigned*)&Bs[NB][bwr2] = pk2(t0_.z, t1_.z);                        \
        *(unsigned*)&Bs[NB][bwr3] = pk2(t0_.w, t1_.w);                        \
    }

#define PIPE_BARRIER()                                                        \
    asm volatile("s_waitcnt lgkmcnt(0)" ::: "memory");                        \
    __builtin_amdgcn_sched_barrier(0);                                        \
    __builtin_amdgcn_s_barrier();                                             \
    __builtin_amdgcn_sched_barrier(0);

#define PIPE_MFMA(CUR)                                                        \
    {                                                                         \
        bf16x8 af_[4], bq_[4];                                                \
        _Pragma("unroll") for (int i = 0; i < 4; i++)                         \
            af_[i] = *(const bf16x8*)&As[CUR][a_rd[i]];                       \
        _Pragma("unroll") for (int i = 0; i < 4; i++)                         \
            bq_[i] = *(const bf16x8*)&Bs[CUR][b_rd[i]];                       \
        _Pragma("unroll") for (int mi = 0; mi < 4; mi++)                      \
            _Pragma("unroll") for (int ni = 0; ni < 4; ni++)                  \
                acc[mi][ni] = __builtin_amdgcn_mfma_f32_16x16x32_bf16(        \
                    af_[mi], bq_[ni], acc[mi][ni], 0, 0, 0);                  \
    }

#define PIPE_BODY(ASRC, BPTR, BSTRIDE, T, CUR, NB1, NB2, RISS, RCON)          \
    {                                                                         \
        bool more_ = (T) + 2 < NIT;                                           \
        if (more_) PIPE_ISSUE(ASRC, BPTR, BSTRIDE, ((T) + 2) * 32, NB2, RISS);\
        PIPE_MFMA(CUR);                                                       \
        if ((T) + 1 < NIT) {                                                  \
            if (more_) { asm volatile("s_waitcnt vmcnt(3)" ::: "memory"); }   \
            else       { asm volatile("s_waitcnt vmcnt(0)" ::: "memory"); }   \
            PIPE_BWRITE(NB1, RCON);                                           \
            PIPE_BARRIER();                                                   \
        }                                                                     \
    }

// B write address: col n = 4*lane + c; wave wv owns k-pair kp=wv ->
// chunk (wv>>2), slot (wv>>2)^sn, intra-chunk dword (wv&3). (shorts)
__device__ __forceinline__ int mk_bwr(int lane, int c, int wv) {
    int n = 4 * lane + c;
    int sn = ((n >> 3) ^ (n >> 5)) & 3;
    return n * 40 + (((wv >> 2) ^ sn) * 8) + (wv & 3) * 2;
}

// ---------------- GEMM1: act = GLU(x[tokens] @ gate_up_w[e] + b) ----------------
__global__ __launch_bounds__(1024, 1) void gemm1_kernel(
    const unsigned short* __restrict__ xb, const float* __restrict__ gw, const float* __restrict__ gb,
    const int* __restrict__ counts, const int* __restrict__ offsets,
    const int* __restrict__ entry, unsigned short* __restrict__ act)
{
    int e = blockIdx.z;
    int cnt = counts[e];
    int m0 = blockIdx.y * 256;
    if (m0 >= cnt) return;
    int n0 = blockIdx.x * 256;
    int off = offsets[e];

    __shared__ __align__(16) unsigned short As[3][256 * 32];  // 16KB x3
    __shared__ __align__(16) unsigned short Bs[3][256 * 40];  // 20KB x3
    __shared__ int toks[256];

    int tid = threadIdx.x;
    if (tid < 256) {
        int r = m0 + tid;
        toks[tid] = entry[off + (r < cnt ? r : 0)] & 0xFFFF;
    }
    __syncthreads();

    int wv = tid >> 6, lane = tid & 63;

    // A gload: wave wv stages rows 16*wv..16*wv+15 (1 inst, 16 rows x 64B)
    int ar = 16 * wv + (lane >> 2);
    int ac = lane & 3;
    const unsigned short* asrc = xb + (size_t)toks[ar] * H_DIM + 8 * (ac ^ ((ar >> 1) & 3));
    int aoff = (16 * wv) * 32;

    // B staging: wave wv = k-row-pair {2wv, 2wv+1}; lane covers cols 4*lane..+3
    int bcol = n0 + 4 * lane;
    int ncc = (bcol < GU_DIM) ? bcol : (GU_DIM - 4);   // ragged last n-tile (5760 % 256 = 128)
    const float* bptr = gw + (size_t)e * H_DIM * GU_DIM + (size_t)(2 * wv) * GU_DIM + ncc;
    int bwr0 = mk_bwr(lane, 0, wv);
    int bwr1 = mk_bwr(lane, 1, wv);
    int bwr2 = mk_bwr(lane, 2, wv);
    int bwr3 = mk_bwr(lane, 3, wv);

    int wm = (wv & 3) * 64, wn = (wv >> 2) * 64;
    int r16 = lane & 15, q = lane >> 4;

    f32x4 acc[4][4] = {};
    int a_rd[4], b_rd[4];
#pragma unroll
    for (int i = 0; i < 4; i++) {
        int m = wm + i * 16 + r16;
        a_rd[i] = m * 32 + ((q ^ ((m >> 1) & 3)) * 8);
        int n = wn + i * 16 + r16;
        int sn = ((n >> 3) ^ (n >> 5)) & 3;
        b_rd[i] = n * 40 + ((q ^ sn) * 8);
    }

    float4 rA[2], rB[2];
    // prologue: tiles 0 and 1 in flight; publish tile 0
    PIPE_ISSUE(asrc, bptr, GU_DIM, 0, 0, rA);
    PIPE_ISSUE(asrc, bptr, GU_DIM, 32, 1, rB);
    asm volatile("s_waitcnt vmcnt(3)" ::: "memory");
    PIPE_BWRITE(0, rA);
    PIPE_BARRIER();

    int c0 = 0;
    for (int it = 0; it < NIT; it += 2) {
        int c1 = c0 + 1; if (c1 == 3) c1 = 0;
        int c2 = c1 + 1; if (c2 == 3) c2 = 0;
        PIPE_BODY(asrc, bptr, GU_DIM, it,     c0, c1, c2, rA, rB);
        PIPE_BODY(asrc, bptr, GU_DIM, it + 1, c1, c2, c0, rB, rA);
        c0 = c2;
    }

    // epilogue: bias + GLU (gate=even col, up=odd col), store bf16 act
    const float* gbp = gb + (size_t)e * GU_DIM;
#pragma unroll
    for (int ni = 0; ni < 4; ni++) {
        int col = n0 + wn + ni * 16 + r16;
        float bias = (col < GU_DIM) ? gbp[col] : 0.f;
#pragma unroll
        for (int mi = 0; mi < 4; mi++) {
#pragma unroll
            for (int r = 0; r < 4; r++) {
                float v = acc[mi][ni][r] + bias;
                float vo = __shfl_xor(v, 1, 64);
                float gate = (lane & 1) ? vo : v;
                float up   = (lane & 1) ? v  : vo;
                gate = fminf(gate, 7.0f);
                up = fminf(fmaxf(up, -7.0f), 7.0f);
                float glu = gate / (1.0f + expf(-1.702f * gate));
                float a = (up + 1.0f) * glu;
                int row = m0 + wm + mi * 16 + q * 4 + r;
                if (row < cnt && col < GU_DIM && !(lane & 1))
                    act[(size_t)(off + row) * F_DIM + (col >> 1)] = f2bf(a);
            }
        }
    }
}

// ---------------- GEMM2: slot_out = score * (act @ down_w[e] + db) ----------------
__global__ __launch_bounds__(1024, 1) void gemm2_kernel(
    const unsigned short* __restrict__ act, const float* __restrict__ dw, const float* __restrict__ db,
    const int* __restrict__ counts, const int* __restrict__ offsets,
    const float* __restrict__ entry_score, float* __restrict__ slot_out)
{
    int e = blockIdx.z;
    int cnt = counts[e];
    int m0 = blockIdx.y * 256;
    if (m0 >= cnt) return;
    int n0 = blockIdx.x * 256;
    int off = offsets[e];

    __shared__ __align__(16) unsigned short As[3][256 * 32];
    __shared__ __align__(16) unsigned short Bs[3][256 * 40];
    __shared__ float scs[256];

    int tid = threadIdx.x;
    if (tid < 256) {
        int r = m0 + tid;
        scs[tid] = entry_score[off + (r < cnt ? r : 0)];
    }
    __syncthreads();

    int wv = tid >> 6, lane = tid & 63;

    int ar = 16 * wv + (lane >> 2);
    int ac = lane & 3;
    const unsigned short* asrc = act + (size_t)(off + m0 + ar) * F_DIM + 8 * (ac ^ ((ar >> 1) & 3));
    int aoff = (16 * wv) * 32;

    int bcol = n0 + 4 * lane;
    int ncc = (bcol < H_DIM) ? bcol : (H_DIM - 4);    // ragged last n-tile (2880 % 256 = 64)
    const float* bptr = dw + (size_t)e * F_DIM * H_DIM + (size_t)(2 * wv) * H_DIM + ncc;
    int bwr0 = mk_bwr(lane, 0, wv);
    int bwr1 = mk_bwr(lane, 1, wv);
    int bwr2 = mk_bwr(lane, 2, wv);
    int bwr3 = mk_bwr(lane, 3, wv);

    int wm = (wv & 3) * 64, wn = (wv >> 2) * 64;
    int r16 = lane & 15, q = lane >> 4;

    f32x4 acc[4][4] = {};
    int a_rd[4], b_rd[4];
#pragma unroll
    for (int i = 0; i < 4; i++) {
        int m = wm + i * 16 + r16;
        a_rd[i] = m * 32 + ((q ^ ((m >> 1) & 3)) * 8);
        int n = wn + i * 16 + r16;
        int sn = ((n >> 3) ^ (n >> 5)) & 3;
        b_rd[i] = n * 40 + ((q ^ sn) * 8);
    }

    float4 rA[2], rB[2];
    PIPE_ISSUE(asrc, bptr, H_DIM, 0, 0, rA);
    PIPE_ISSUE(asrc, bptr, H_DIM, 32, 1, rB);
    asm volatile("s_waitcnt vmcnt(3)" ::: "memory");
    PIPE_BWRITE(0, rA);
    PIPE_BARRIER();

    int c0 = 0;
    for (int it = 0; it < NIT; it += 2) {
        int c1 = c0 + 1; if (c1 == 3) c1 = 0;
        int c2 = c1 + 1; if (c2 == 3) c2 = 0;
        PIPE_BODY(asrc, bptr, H_DIM, it,     c0, c1, c2, rA, rB);
        PIPE_BODY(asrc, bptr, H_DIM, it + 1, c1, c2, c0, rB, rA);
        c0 = c2;
    }

    const float* dbp = db + (size_t)e * H_DIM;
#pragma unroll
    for (int ni = 0; ni < 4; ni++) {
        int col = n0 + wn + ni * 16 + r16;
        float bias = (col < H_DIM) ? dbp[col] : 0.f;
#pragma unroll
        for (int mi = 0; mi < 4; mi++) {
#pragma unroll
            for (int r = 0; r < 4; r++) {
                int lr = wm + mi * 16 + q * 4 + r;
                if (m0 + lr < cnt && col < H_DIM) {
                    float v = (acc[mi][ni][r] + bias) * scs[lr];
                    slot_out[(size_t)(off + m0 + lr) * H_DIM + col] = v;
                }
            }
        }
    }
}

// ---------------- gather: out[t] = sum of the token's 4 slot rows ----------------
__global__ __launch_bounds__(256) void gather_kernel(
    const float* __restrict__ slot_out, const int* __restrict__ slot_map,
    float* __restrict__ out)
{
    int t = blockIdx.x;
    int s0 = slot_map[t * TOPK + 0];
    int s1 = slot_map[t * TOPK + 1];
    int s2 = slot_map[t * TOPK + 2];
    int s3 = slot_map[t * TOPK + 3];
    const float* r0 = slot_out + (size_t)s0 * H_DIM;
    const float* r1 = slot_out + (size_t)s1 * H_DIM;
    const float* r2 = slot_out + (size_t)s2 * H_DIM;
    const float* r3 = slot_out + (size_t)s3 * H_DIM;
    float* op = out + (size_t)t * H_DIM;
    for (int h = threadIdx.x * 4; h < H_DIM; h += 1024) {
        f32x4 v = *(const f32x4*)(r0 + h) + *(const f32x4*)(r1 + h)
                + *(const f32x4*)(r2 + h) + *(const f32x4*)(r3 + h);
        *(f32x4*)(op + h) = v;
    }
}

// ---------------- launch ----------------
extern "C" void kernel_launch(void* const* d_in, const int* in_sizes, int n_in,
                              void* d_out, int out_size, void* d_ws, size_t ws_size,
                              hipStream_t stream)
{
    const float* x  = (const float*)d_in[0];
    const float* rw = (const float*)d_in[1];
    const float* rb = (const float*)d_in[2];
    const float* gw = (const float*)d_in[3];
    const float* gb = (const float*)d_in[4];
    const float* dw = (const float*)d_in[5];
    const float* db = (const float*)d_in[6];
    float* out = (float*)d_out;

    char* ws = (char*)d_ws;
    int*   counts      = (int*)(ws);
    int*   fills       = (int*)(ws + 64);
    int*   offsets     = (int*)(ws + 128);
    int*   topk_idx    = (int*)(ws + 256);
    float* topk_score  = (float*)(ws + 16640);
    int*   entry       = (int*)(ws + 33024);
    float* entry_score = (float*)(ws + 49408);
    int*   slot_map    = (int*)(ws + 65792);
    unsigned short* act = (unsigned short*)(ws + 131072);   // 4352 x 2880 bf16 (256-row slack for gload overread)
    unsigned short* xb  = (unsigned short*)(ws + 25198592); // 1024 x 2880 bf16
    float* slot_out     = (float*)(ws + 31096832);          // 4096 x 2880 f32

    hipMemsetAsync(ws, 0, 256, stream);   // counts + fills

    castx_kernel<<<1440, 256, 0, stream>>>(x, xb);
    router_kernel<<<NT, 64, 0, stream>>>(x, rw, rb, counts, topk_idx, topk_score);
    offsets_kernel<<<1, 32, 0, stream>>>(counts, offsets);
    scatter_kernel<<<4, 256, 0, stream>>>(topk_idx, topk_score, offsets, fills, entry, entry_score, slot_map);
    gemm1_kernel<<<dim3(23, 4, NE), 1024, 0, stream>>>(xb, gw, gb, counts, offsets, entry, act);
    gemm2_kernel<<<dim3(12, 4, NE), 1024, 0, stream>>>(act, dw, db, counts, offsets, entry_score, slot_out);
    gather_kernel<<<NT, 256, 0, stream>>>(slot_out, slot_map, out);
}